// Round 19
// baseline (933.372 us; speedup 1.0000x reference)
//
#include <hip/hip_runtime.h>
#include <float.h>

#define NS 1536
#define DD 64

// ws layout (float elements)
static const size_t OFF_A  = 0;                          // A = h_sat + b1: [1536][64]
static const size_t OFF_C2 = 98304;                      // C2 = h_uav transposed [16][1536][4]
static const size_t OFF_L  = 196608;                     // logits [1536][1536]
static const size_t OFF_AS = 196608 + (size_t)NS * NS;   // int assign [1536]
// top_lo (ranks 0-255, ushort, 786432 B) ALIASES A/C2 (dead after kB).
// top_hi (ranks 256-511, ushort, 786432 B) lives in D_OUT (dead until kE,
// which fully overwrites it after kD has consumed it — stream-ordered).

// ---------------- Kernel A: first-layer projections ----------------
__global__ __launch_bounds__(64) void kA(const float* __restrict__ sat,
                                         const float* __restrict__ uav,
                                         const float* __restrict__ W1,
                                         const float* __restrict__ b1,
                                         float* __restrict__ A,
                                         float* __restrict__ C2) {
    const int row = blockIdx.x;
    const int d = threadIdx.x;
    float accA = b1[d];
    float accC = 0.f;
    const float* __restrict__ satr = sat + row * DD;
    const float* __restrict__ uavr = uav + row * DD;
#pragma unroll 8
    for (int k = 0; k < DD; ++k) {
        accA = fmaf(satr[k], W1[k * DD + d], accA);
        accC = fmaf(uavr[k], W1[(DD + k) * DD + d], accC);
    }
    A[row * DD + d] = accA;
    C2[((size_t)(d >> 2) * NS + row) * 4 + (d & 3)] = accC;
}

// ---------------- Kernel B: all-pairs logits ----------------
__global__ __launch_bounds__(256) void kB(const float* __restrict__ A,
                                          const float* __restrict__ C2,
                                          const float* __restrict__ W2,
                                          const float* __restrict__ b2,
                                          const float* __restrict__ W3,
                                          float* __restrict__ L) {
    const int lane = threadIdx.x & 63;
    const int wave = threadIdx.x >> 6;
    const int i = __builtin_amdgcn_readfirstlane(blockIdx.x * 4 + wave);
    const int jbase = blockIdx.y * 256;
    const float* __restrict__ Ar = A + (size_t)i * DD;

    float u[4][32];
#pragma unroll
    for (int o = 0; o < 32; ++o) {
        const float b = b2[o];
        u[0][o] = b; u[1][o] = b; u[2][o] = b; u[3][o] = b;
    }

    const float4* __restrict__ C2v = (const float4*)C2;

    for (int d4 = 0; d4 < 16; ++d4) {
        float c[4][4];
#pragma unroll
        for (int p = 0; p < 4; ++p) {
            const float4 t = C2v[(size_t)d4 * NS + jbase + p * 64 + lane];
            c[p][0] = t.x; c[p][1] = t.y; c[p][2] = t.z; c[p][3] = t.w;
        }
#pragma unroll
        for (int dd = 0; dd < 4; ++dd) {
            const float a = Ar[d4 * 4 + dd];
            const float v0 = fmaxf(a + c[0][dd], 0.f);
            const float v1 = fmaxf(a + c[1][dd], 0.f);
            const float v2 = fmaxf(a + c[2][dd], 0.f);
            const float v3 = fmaxf(a + c[3][dd], 0.f);
            const float* __restrict__ w2r = W2 + (d4 * 4 + dd) * 32;
#pragma unroll
            for (int o = 0; o < 32; ++o) {
                const float w = w2r[o];
                u[0][o] = fmaf(v0, w, u[0][o]);
                u[1][o] = fmaf(v1, w, u[1][o]);
                u[2][o] = fmaf(v2, w, u[2][o]);
                u[3][o] = fmaf(v3, w, u[3][o]);
            }
        }
    }

#pragma unroll
    for (int p = 0; p < 4; ++p) {
        float acc = 0.f;
#pragma unroll
        for (int o = 0; o < 32; ++o)
            acc = fmaf(fmaxf(u[p][o], 0.f), W3[o], acc);
        L[(size_t)i * NS + jbase + p * 64 + lane] = acc;
    }
}

// ---------------- Kernel C: per-row sorted top-512 via 16-bit radix ----------------
// Ranks 0-255 -> top_lo (swizzled: rank r at row*256+(r&63)*4+(r>>6));
// ranks 256-511 -> top_hi (same swizzle on r-256). Sentinel 0xFFFF on both
// (m>1024 overflow rows keep sentinels -> kD full-fallback, exact).
__global__ __launch_bounds__(256) void kC(const float* __restrict__ L,
                                          unsigned short* __restrict__ top,
                                          unsigned short* __restrict__ toph) {
    __shared__ int hist[256];
    __shared__ int suff[256];
    __shared__ float cv[1024];
    __shared__ int ci[1024];
    __shared__ int s_cnt, s_B0, s_base, s_B1;
    const int t = threadIdx.x;
    const int row = blockIdx.x;
    const float* __restrict__ Lr = L + (size_t)row * NS;

    top[row * 256 + t]  = 0xFFFFu;
    toph[row * 256 + t] = 0xFFFFu;

    hist[t] = 0;
    if (t == 0) s_cnt = 0;
    __syncthreads();

    unsigned ub[6]; float fv[6];
#pragma unroll
    for (int k = 0; k < 6; ++k) {
        const float x = Lr[t + 256 * k];
        fv[k] = x;
        unsigned b = __float_as_uint(x);
        b = (b & 0x80000000u) ? ~b : (b | 0x80000000u);
        ub[k] = b;
        atomicAdd(&hist[b >> 24], 1);
    }
    __syncthreads();

    suff[t] = hist[t];
    __syncthreads();
    for (int off = 1; off < 256; off <<= 1) {
        const int v = (t + off < 256) ? suff[t + off] : 0;
        __syncthreads();
        suff[t] += v;
        __syncthreads();
    }
    if (suff[t] >= 512 && (t == 255 || suff[t + 1] < 512)) {
        s_B0 = t;
        s_base = (t == 255) ? 0 : suff[t + 1];
    }
    __syncthreads();
    const unsigned B0 = (unsigned)s_B0;
    const int base = s_base;

    hist[t] = 0;
    __syncthreads();
#pragma unroll
    for (int k = 0; k < 6; ++k)
        if ((ub[k] >> 24) == B0) atomicAdd(&hist[(ub[k] >> 16) & 255], 1);
    __syncthreads();
    suff[t] = hist[t];
    __syncthreads();
    for (int off = 1; off < 256; off <<= 1) {
        const int v = (t + off < 256) ? suff[t + off] : 0;
        __syncthreads();
        suff[t] += v;
        __syncthreads();
    }
    const int need = 512 - base;
    if (suff[t] >= need && (t == 255 || suff[t + 1] < need)) s_B1 = t;
    __syncthreads();
    const unsigned B1 = (unsigned)s_B1;
    const int m = base + suff[B1];
    if (m > 1024) return;

#pragma unroll
    for (int k = 0; k < 6; ++k) {
        const unsigned hi = ub[k] >> 24;
        const unsigned mid = (ub[k] >> 16) & 255u;
        if (hi > B0 || (hi == B0 && mid >= B1)) {
            const int pos = atomicAdd(&s_cnt, 1);
            cv[pos] = fv[k];
            ci[pos] = t + 256 * k;
        }
    }
    __syncthreads();

    for (int e = t; e < m; e += 256) {
        const float v = cv[e]; const int id = ci[e];
        int r = 0;
        for (int s2 = 0; s2 < m; ++s2) {
            const float vs = cv[s2];
            if (vs > v || (vs == v && ci[s2] < id)) ++r;
        }
        if (r < 256)
            top[row * 256 + (r & 63) * 4 + (r >> 6)] = (unsigned short)id;
        else if (r < 512) {
            const int r2 = r - 256;
            toph[row * 256 + (r2 & 63) * 4 + (r2 >> 6)] = (unsigned short)id;
        }
    }
}

// Wave-wide max of a u32 via DPP (pure VALU). bound_ctrl=true fills invalid
// source lanes with 0 -> safe identity (all keys used are > 0).
__device__ __forceinline__ unsigned wave_max_u32_dpp(unsigned x) {
    unsigned t;
    t = (unsigned)__builtin_amdgcn_update_dpp(0, (int)x, 0x111, 0xF, 0xF, true); // row_shr:1
    x = x > t ? x : t;
    t = (unsigned)__builtin_amdgcn_update_dpp(0, (int)x, 0x112, 0xF, 0xF, true); // row_shr:2
    x = x > t ? x : t;
    t = (unsigned)__builtin_amdgcn_update_dpp(0, (int)x, 0x114, 0xF, 0xF, true); // row_shr:4
    x = x > t ? x : t;
    t = (unsigned)__builtin_amdgcn_update_dpp(0, (int)x, 0x118, 0xF, 0xF, true); // row_shr:8
    x = x > t ? x : t;
    t = (unsigned)__builtin_amdgcn_update_dpp(0, (int)x, 0x142, 0xF, 0xF, true); // row_bcast:15
    x = x > t ? x : t;
    t = (unsigned)__builtin_amdgcn_update_dpp(0, (int)x, 0x143, 0xF, 0xF, true); // row_bcast:31
    x = x > t ? x : t;
    return x;
}

__device__ __forceinline__ int dpp_argmax(float bv, int bi) {
    unsigned b = __float_as_uint(bv);
    unsigned key = (b & 0x80000000u) ? ~b : (b | 0x80000000u);
    const unsigned wk = wave_max_u32_dpp(key);
    const unsigned maxk = (unsigned)__builtin_amdgcn_readlane((int)wk, 63);
    unsigned cand = (key == maxk) ? (unsigned)(NS - bi) : 0u;
    const unsigned wc = wave_max_u32_dpp(cand);
    const unsigned mc = (unsigned)__builtin_amdgcn_readlane((int)wc, 63);
    return NS - (int)mc;
}

// Exact masked argmax over the compact unused list (r15 champion form).
__device__ __forceinline__ int fb_argmax(const float* __restrict__ L, int i,
                                         int mU, const int (&U16)[16],
                                         const int* used_s,
                                         const unsigned short* U_s, int lane) {
    const float* __restrict__ Lr = L + (size_t)i * NS;
    float bv = -FLT_MAX; int bi = NS;
    {
        int idx[8]; int flc[8]; float vv[8];
#pragma unroll
        for (int c = 0; c < 8; ++c) {
            const int k = lane + (c << 6);
            idx[c] = (k < mU) ? U16[c] : 0;
        }
#pragma unroll
        for (int c = 0; c < 8; ++c) vv[c] = Lr[idx[c]];     // addr from regs
#pragma unroll
        for (int c = 0; c < 8; ++c) flc[c] = used_s[idx[c]];
#pragma unroll
        for (int c = 0; c < 8; ++c) {
            const int k = lane + (c << 6);
            if (k < mU && flc[c] == 0 &&
                (vv[c] > bv || (vv[c] == bv && idx[c] < bi))) {
                bv = vv[c]; bi = idx[c];
            }
        }
    }
    for (int kbase = 512; kbase < mU; kbase += 512) {
        int idx[8]; int flc[8]; float vv[8];
#pragma unroll
        for (int c = 0; c < 8; ++c) {
            const int k = kbase + lane + (c << 6);
            idx[c] = (k < mU) ? (int)U_s[k] : 0;
        }
#pragma unroll
        for (int c = 0; c < 8; ++c) flc[c] = used_s[idx[c]];
#pragma unroll
        for (int c = 0; c < 8; ++c) vv[c] = Lr[idx[c]];
#pragma unroll
        for (int c = 0; c < 8; ++c) {
            const int k = kbase + lane + (c << 6);
            if (k < mU && flc[c] == 0 &&
                (vv[c] > bv || (vv[c] == bv && idx[c] < bi))) {
                bv = vv[c]; bi = idx[c];
            }
        }
    }
    return dpp_argmax(bv, bi);
}

// ---------------- Kernel D: sequential greedy (single wave) ----------------
// r15 champion + CASCADED top-512 ballot: ranks 0-255 (bufL) checked first;
// on miss, ranks 256-511 (bufH, stored in d_out scratch) — wave-uniform
// branch (ballot results uniform). Upgrades ~300-400 late rows from the
// ~900cy fallback to a ~300cy hi-ballot. Prefix-of-sorted-order exactness:
// first free candidate by rank = argmax; stale-by-one flags corrected via
// jprev; fallback (U16 + DPP) remains the exact general path; TIGHT mode
// unchanged.
__global__ __launch_bounds__(64) void kD(const float* __restrict__ L,
                                         const unsigned short* __restrict__ top,
                                         const unsigned short* __restrict__ toph,
                                         int* __restrict__ assign) {
    __shared__ int used_s[NS];
    __shared__ int assign_s[NS];
    __shared__ unsigned short U_s[NS];
    const int lane = threadIdx.x;
    for (int k = lane; k < NS; k += 64) used_s[k] = 0;
    __syncthreads();

    const uint2* __restrict__ T  = (const uint2*)top;    // T[row*64 + lane]
    const uint2* __restrict__ Th = (const uint2*)toph;

    uint2 bufL[16], bufH[16];          // rows g..g+15
#pragma unroll
    for (int k = 0; k < 16; ++k) bufL[k] = T[k * 64 + lane];
#pragma unroll
    for (int k = 0; k < 16; ++k) bufH[k] = Th[k * 64 + lane];

    int f0 = 0, f1 = 0, f2 = 0, f3 = 0;   // row-0 flags (lo ranks)
    int f4 = 0, f5 = 0, f6 = 0, f7 = 0;   // row-0 flags (hi ranks)
    int jprev = -1;
    int mU = NS;
    int U16[16];
    bool tight = false;

    for (int g = 0; g < NS; g += 8) {
        // ---- rebuild compact unused list every 64 rows ----
        if ((g & 63) == 0) {
            int fl[24];
#pragma unroll
            for (int k = 0; k < 24; ++k) fl[k] = used_s[lane + (k << 6)];
            int cnt = 0;
#pragma unroll
            for (int k = 0; k < 24; ++k) cnt += (fl[k] == 0);
            int incl = cnt;
#pragma unroll
            for (int o = 1; o < 64; o <<= 1) {
                const int v = __shfl_up(incl, o);
                if (lane >= o) incl += v;
            }
            int pos = incl - cnt;   // exclusive prefix
#pragma unroll
            for (int k = 0; k < 24; ++k) {
                if (fl[k] == 0) { U_s[pos] = (unsigned short)(lane + (k << 6)); ++pos; }
            }
            mU = __builtin_amdgcn_readlane(incl, 63);
#pragma unroll
            for (int c = 0; c < 16; ++c) U16[c] = (int)U_s[lane + (c << 6)];
        }

        if (!tight) {
            // issue T loads for rows g+16..g+23 (consumed 2 groups from now)
            uint2 nbL[8], nbH[8];
#pragma unroll
            for (int k = 0; k < 8; ++k) {
                int r = g + 16 + k;
                r = (r < NS) ? r : (NS - 1);
                nbL[k] = T[r * 64 + lane];
                nbH[k] = Th[r * 64 + lane];
            }

            int fbcnt = 0;
#pragma unroll
            for (int q = 0; q < 8; ++q) {
                const int i = g + q;

                // prefetch used-flags for row i+1 (8 candidates resident)
                const uint2 pn  = bufL[q + 1];
                const uint2 pnh = bufH[q + 1];
                const int n0 = (int)(pn.x & 0xFFFFu),  n1 = (int)(pn.x >> 16);
                const int n2 = (int)(pn.y & 0xFFFFu),  n3 = (int)(pn.y >> 16);
                const int n4 = (int)(pnh.x & 0xFFFFu), n5 = (int)(pnh.x >> 16);
                const int n6 = (int)(pnh.y & 0xFFFFu), n7 = (int)(pnh.y >> 16);
                const int g0 = used_s[n0 < NS ? n0 : 0];
                const int g1 = used_s[n1 < NS ? n1 : 0];
                const int g2 = used_s[n2 < NS ? n2 : 0];
                const int g3 = used_s[n3 < NS ? n3 : 0];
                const int g4 = used_s[n4 < NS ? n4 : 0];
                const int g5 = used_s[n5 < NS ? n5 : 0];
                const int g6 = used_s[n6 < NS ? n6 : 0];
                const int g7 = used_s[n7 < NS ? n7 : 0];

                const uint2 pc  = bufL[q];
                const uint2 pch = bufH[q];
                const int c0 = (int)(pc.x & 0xFFFFu),  c1 = (int)(pc.x >> 16);
                const int c2 = (int)(pc.y & 0xFFFFu),  c3 = (int)(pc.y >> 16);
                const bool a0 = (c0 < NS) && (f0 == 0) && (c0 != jprev);
                const bool a1 = (c1 < NS) && (f1 == 0) && (c1 != jprev);
                const bool a2 = (c2 < NS) && (f2 == 0) && (c2 != jprev);
                const bool a3 = (c3 < NS) && (f3 == 0) && (c3 != jprev);
                const unsigned long long b0 = __ballot(a0);
                const unsigned long long b1 = __ballot(a1);
                const unsigned long long b2 = __ballot(a2);
                const unsigned long long b3 = __ballot(a3);

                int j;
                if (b0)      j = __builtin_amdgcn_readlane(c0, __ffsll(b0) - 1);
                else if (b1) j = __builtin_amdgcn_readlane(c1, __ffsll(b1) - 1);
                else if (b2) j = __builtin_amdgcn_readlane(c2, __ffsll(b2) - 1);
                else if (b3) j = __builtin_amdgcn_readlane(c3, __ffsll(b3) - 1);
                else {
                    // ---- hi cascade (ranks 256-511), wave-uniform branch ----
                    const int c4 = (int)(pch.x & 0xFFFFu), c5 = (int)(pch.x >> 16);
                    const int c6 = (int)(pch.y & 0xFFFFu), c7 = (int)(pch.y >> 16);
                    const bool a4 = (c4 < NS) && (f4 == 0) && (c4 != jprev);
                    const bool a5 = (c5 < NS) && (f5 == 0) && (c5 != jprev);
                    const bool a6 = (c6 < NS) && (f6 == 0) && (c6 != jprev);
                    const bool a7 = (c7 < NS) && (f7 == 0) && (c7 != jprev);
                    const unsigned long long b4 = __ballot(a4);
                    const unsigned long long b5 = __ballot(a5);
                    const unsigned long long b6 = __ballot(a6);
                    const unsigned long long b7 = __ballot(a7);
                    if (b4)      j = __builtin_amdgcn_readlane(c4, __ffsll(b4) - 1);
                    else if (b5) j = __builtin_amdgcn_readlane(c5, __ffsll(b5) - 1);
                    else if (b6) j = __builtin_amdgcn_readlane(c6, __ffsll(b6) - 1);
                    else if (b7) j = __builtin_amdgcn_readlane(c7, __ffsll(b7) - 1);
                    else {
                        ++fbcnt;
                        j = fb_argmax(L, i, mU, U16, used_s, U_s, lane);
                    }
                }
                if (lane == 0) { used_s[j] = 1; assign_s[i] = j; }
                jprev = j;
                f0 = g0; f1 = g1; f2 = g2; f3 = g3;
                f4 = g4; f5 = g5; f6 = g6; f7 = g7;
            }

            // rotate: waits only for loads issued ~8 rows ago (fully landed)
#pragma unroll
            for (int k = 0; k < 8; ++k) { bufL[k] = bufL[k + 8]; bufH[k] = bufH[k + 8]; }
#pragma unroll
            for (int k = 0; k < 8; ++k) { bufL[k + 8] = nbL[k]; bufH[k + 8] = nbH[k]; }

            tight = (fbcnt == 8);   // full-group fallback -> ballots are dead
        } else {
            // ---- TIGHT mode: fallback-only, no ballot preamble/prefetch ----
#pragma unroll 1
            for (int q = 0; q < 8; ++q) {
                const int i = g + q;
                const int j = fb_argmax(L, i, mU, U16, used_s, U_s, lane);
                if (lane == 0) { used_s[j] = 1; assign_s[i] = j; }
            }
        }
    }

    for (int k = lane; k < NS; k += 64) assign[k] = assign_s[k];
}

// ---------------- Kernel E: emit [1536][2][64] output ----------------
// Fully overwrites d_out (which kC/kD used as top_hi scratch).
__global__ __launch_bounds__(128) void kE(const float* __restrict__ sat,
                                          const float* __restrict__ uav,
                                          const int* __restrict__ assign,
                                          float* __restrict__ out) {
    const int i = blockIdx.x;
    const int t = threadIdx.x;
    if (t < 64) out[(size_t)i * 128 + t] = sat[(size_t)i * DD + t];
    else        out[(size_t)i * 128 + t] = uav[(size_t)assign[i] * DD + (t - 64)];
}

extern "C" void kernel_launch(void* const* d_in, const int* in_sizes, int n_in,
                              void* d_out, int out_size, void* d_ws, size_t ws_size,
                              hipStream_t stream) {
    const float* sat = (const float*)d_in[0];
    const float* uav = (const float*)d_in[1];
    const float* W1  = (const float*)d_in[2];
    const float* b1  = (const float*)d_in[3];
    const float* W2  = (const float*)d_in[4];
    const float* b2  = (const float*)d_in[5];
    const float* W3  = (const float*)d_in[6];
    // d_in[7] = b3: sigmoid(x+b3) monotone in x — argmax unchanged.

    float* ws = (float*)d_ws;
    float* A   = ws + OFF_A;
    float* C2  = ws + OFF_C2;
    float* L   = ws + OFF_L;
    int* assign = (int*)(ws + OFF_AS);
    unsigned short* top  = (unsigned short*)(ws + OFF_A); // aliases A/C2 (dead after kB)
    unsigned short* toph = (unsigned short*)d_out;        // d_out scratch (dead until kE)

    hipLaunchKernelGGL(kA, dim3(NS), dim3(64), 0, stream, sat, uav, W1, b1, A, C2);
    hipLaunchKernelGGL(kB, dim3(NS / 4, NS / 256), dim3(256), 0, stream,
                       A, C2, W2, b2, W3, L);
    hipLaunchKernelGGL(kC, dim3(NS), dim3(256), 0, stream, L, top, toph);
    hipLaunchKernelGGL(kD, dim3(1), dim3(64), 0, stream, L, top, toph, assign);
    hipLaunchKernelGGL(kE, dim3(NS), dim3(128), 0, stream, sat, uav, assign,
                       (float*)d_out);
}

// Round 20
// 803.986 us; speedup vs baseline: 1.1609x; 1.1609x over previous
//
#include <hip/hip_runtime.h>
#include <float.h>

#define NS 1536
#define DD 64

// ws layout (float elements)
static const size_t OFF_A  = 0;                          // A = h_sat + b1: [1536][64]
static const size_t OFF_C2 = 98304;                      // C2 = h_uav transposed [16][1536][4]
static const size_t OFF_L  = 196608;                     // logits [1536][1536]
static const size_t OFF_AS = 196608 + (size_t)NS * NS;   // int assign [1536]
// top_idx (ushort, 1536*256 = 786432 B) ALIASES the A/C2 region (dead after kB).

// ---------------- Kernel A: first-layer projections ----------------
__global__ __launch_bounds__(64) void kA(const float* __restrict__ sat,
                                         const float* __restrict__ uav,
                                         const float* __restrict__ W1,
                                         const float* __restrict__ b1,
                                         float* __restrict__ A,
                                         float* __restrict__ C2) {
    const int row = blockIdx.x;
    const int d = threadIdx.x;
    float accA = b1[d];
    float accC = 0.f;
    const float* __restrict__ satr = sat + row * DD;
    const float* __restrict__ uavr = uav + row * DD;
#pragma unroll 8
    for (int k = 0; k < DD; ++k) {
        accA = fmaf(satr[k], W1[k * DD + d], accA);
        accC = fmaf(uavr[k], W1[(DD + k) * DD + d], accC);
    }
    A[row * DD + d] = accA;
    C2[((size_t)(d >> 2) * NS + row) * 4 + (d & 3)] = accC;
}

// ---------------- Kernel B: all-pairs logits ----------------
__global__ __launch_bounds__(256) void kB(const float* __restrict__ A,
                                          const float* __restrict__ C2,
                                          const float* __restrict__ W2,
                                          const float* __restrict__ b2,
                                          const float* __restrict__ W3,
                                          float* __restrict__ L) {
    const int lane = threadIdx.x & 63;
    const int wave = threadIdx.x >> 6;
    const int i = __builtin_amdgcn_readfirstlane(blockIdx.x * 4 + wave);
    const int jbase = blockIdx.y * 256;
    const float* __restrict__ Ar = A + (size_t)i * DD;

    float u[4][32];
#pragma unroll
    for (int o = 0; o < 32; ++o) {
        const float b = b2[o];
        u[0][o] = b; u[1][o] = b; u[2][o] = b; u[3][o] = b;
    }

    const float4* __restrict__ C2v = (const float4*)C2;

    for (int d4 = 0; d4 < 16; ++d4) {
        float c[4][4];
#pragma unroll
        for (int p = 0; p < 4; ++p) {
            const float4 t = C2v[(size_t)d4 * NS + jbase + p * 64 + lane];
            c[p][0] = t.x; c[p][1] = t.y; c[p][2] = t.z; c[p][3] = t.w;
        }
#pragma unroll
        for (int dd = 0; dd < 4; ++dd) {
            const float a = Ar[d4 * 4 + dd];
            const float v0 = fmaxf(a + c[0][dd], 0.f);
            const float v1 = fmaxf(a + c[1][dd], 0.f);
            const float v2 = fmaxf(a + c[2][dd], 0.f);
            const float v3 = fmaxf(a + c[3][dd], 0.f);
            const float* __restrict__ w2r = W2 + (d4 * 4 + dd) * 32;
#pragma unroll
            for (int o = 0; o < 32; ++o) {
                const float w = w2r[o];
                u[0][o] = fmaf(v0, w, u[0][o]);
                u[1][o] = fmaf(v1, w, u[1][o]);
                u[2][o] = fmaf(v2, w, u[2][o]);
                u[3][o] = fmaf(v3, w, u[3][o]);
            }
        }
    }

#pragma unroll
    for (int p = 0; p < 4; ++p) {
        float acc = 0.f;
#pragma unroll
        for (int o = 0; o < 32; ++o)
            acc = fmaf(fmaxf(u[p][o], 0.f), W3[o], acc);
        L[(size_t)i * NS + jbase + p * 64 + lane] = acc;
    }
}

// ---------------- Kernel C: per-row sorted top-256 via 16-bit radix ----------------
// Swizzled layout: rank r lives at top[row*256 + (r&63)*4 + (r>>6)] so kD's
// uint2-per-lane read gives lane l ranks {l, l+64, l+128, l+192}.
__global__ __launch_bounds__(256) void kC(const float* __restrict__ L,
                                          unsigned short* __restrict__ top) {
    __shared__ int hist[256];
    __shared__ int suff[256];
    __shared__ float cv[1024];
    __shared__ int ci[1024];
    __shared__ int s_cnt, s_B0, s_base, s_B1;
    const int t = threadIdx.x;
    const int row = blockIdx.x;
    const float* __restrict__ Lr = L + (size_t)row * NS;

    top[row * 256 + t] = 0xFFFFu;   // sentinel (degenerate rows -> kD fallback)

    hist[t] = 0;
    if (t == 0) s_cnt = 0;
    __syncthreads();

    unsigned ub[6]; float fv[6];
#pragma unroll
    for (int k = 0; k < 6; ++k) {
        const float x = Lr[t + 256 * k];
        fv[k] = x;
        unsigned b = __float_as_uint(x);
        b = (b & 0x80000000u) ? ~b : (b | 0x80000000u);
        ub[k] = b;
        atomicAdd(&hist[b >> 24], 1);
    }
    __syncthreads();

    suff[t] = hist[t];
    __syncthreads();
    for (int off = 1; off < 256; off <<= 1) {
        const int v = (t + off < 256) ? suff[t + off] : 0;
        __syncthreads();
        suff[t] += v;
        __syncthreads();
    }
    if (suff[t] >= 256 && (t == 255 || suff[t + 1] < 256)) {
        s_B0 = t;
        s_base = (t == 255) ? 0 : suff[t + 1];
    }
    __syncthreads();
    const unsigned B0 = (unsigned)s_B0;
    const int base = s_base;

    hist[t] = 0;
    __syncthreads();
#pragma unroll
    for (int k = 0; k < 6; ++k)
        if ((ub[k] >> 24) == B0) atomicAdd(&hist[(ub[k] >> 16) & 255], 1);
    __syncthreads();
    suff[t] = hist[t];
    __syncthreads();
    for (int off = 1; off < 256; off <<= 1) {
        const int v = (t + off < 256) ? suff[t + off] : 0;
        __syncthreads();
        suff[t] += v;
        __syncthreads();
    }
    const int need = 256 - base;
    if (suff[t] >= need && (t == 255 || suff[t + 1] < need)) s_B1 = t;
    __syncthreads();
    const unsigned B1 = (unsigned)s_B1;
    const int m = base + suff[B1];
    if (m > 1024) return;

#pragma unroll
    for (int k = 0; k < 6; ++k) {
        const unsigned hi = ub[k] >> 24;
        const unsigned mid = (ub[k] >> 16) & 255u;
        if (hi > B0 || (hi == B0 && mid >= B1)) {
            const int pos = atomicAdd(&s_cnt, 1);
            cv[pos] = fv[k];
            ci[pos] = t + 256 * k;
        }
    }
    __syncthreads();

    for (int e = t; e < m; e += 256) {
        const float v = cv[e]; const int id = ci[e];
        int r = 0;
        for (int s2 = 0; s2 < m; ++s2) {
            const float vs = cv[s2];
            if (vs > v || (vs == v && ci[s2] < id)) ++r;
        }
        if (r < 256) top[row * 256 + (r & 63) * 4 + (r >> 6)] = (unsigned short)id;
    }
}

// Wave-wide max of a u32 via DPP (pure VALU, ~4-8cy/stage vs ~60cy/bpermute).
// bound_ctrl=true fills invalid source lanes with 0 -> 0 must be a safe
// identity (all our keys are > 0). Lane 63 holds the wave max afterwards.
__device__ __forceinline__ unsigned wave_max_u32_dpp(unsigned x) {
    unsigned t;
    t = (unsigned)__builtin_amdgcn_update_dpp(0, (int)x, 0x111, 0xF, 0xF, true); // row_shr:1
    x = x > t ? x : t;
    t = (unsigned)__builtin_amdgcn_update_dpp(0, (int)x, 0x112, 0xF, 0xF, true); // row_shr:2
    x = x > t ? x : t;
    t = (unsigned)__builtin_amdgcn_update_dpp(0, (int)x, 0x114, 0xF, 0xF, true); // row_shr:4
    x = x > t ? x : t;
    t = (unsigned)__builtin_amdgcn_update_dpp(0, (int)x, 0x118, 0xF, 0xF, true); // row_shr:8
    x = x > t ? x : t;
    t = (unsigned)__builtin_amdgcn_update_dpp(0, (int)x, 0x142, 0xF, 0xF, true); // row_bcast:15
    x = x > t ? x : t;
    t = (unsigned)__builtin_amdgcn_update_dpp(0, (int)x, 0x143, 0xF, 0xF, true); // row_bcast:31
    x = x > t ? x : t;
    return x;
}

__device__ __forceinline__ int dpp_argmax(float bv, int bi) {
    unsigned b = __float_as_uint(bv);
    unsigned key = (b & 0x80000000u) ? ~b : (b | 0x80000000u);
    const unsigned wk = wave_max_u32_dpp(key);
    const unsigned maxk = (unsigned)__builtin_amdgcn_readlane((int)wk, 63);
    unsigned cand = (key == maxk) ? (unsigned)(NS - bi) : 0u;
    const unsigned wc = wave_max_u32_dpp(cand);
    const unsigned mc = (unsigned)__builtin_amdgcn_readlane((int)wc, 63);
    return NS - (int)mc;
}

// Exact masked argmax over the compact unused list (r15-proven champion form).
// Chunk 0 indices from the U16 register cache (first 8 entries); chunks >=512
// (early rows only) from U_s in LDS. Value gather and flag gather issue
// back-to-back: the ~150cy LDS flag latency hides under the ~500cy L3 value
// gather (r17 proved removing the flag reads is net-negative).
__device__ __forceinline__ int fb_argmax(const float* __restrict__ L, int i,
                                         int mU, const int (&U16)[16],
                                         const int* used_s,
                                         const unsigned short* U_s, int lane) {
    const float* __restrict__ Lr = L + (size_t)i * NS;
    float bv = -FLT_MAX; int bi = NS;
    {
        int idx[8]; int flc[8]; float vv[8];
#pragma unroll
        for (int c = 0; c < 8; ++c) {
            const int k = lane + (c << 6);
            idx[c] = (k < mU) ? U16[c] : 0;
        }
#pragma unroll
        for (int c = 0; c < 8; ++c) vv[c] = Lr[idx[c]];     // addr from regs
#pragma unroll
        for (int c = 0; c < 8; ++c) flc[c] = used_s[idx[c]];
#pragma unroll
        for (int c = 0; c < 8; ++c) {
            const int k = lane + (c << 6);
            if (k < mU && flc[c] == 0 &&
                (vv[c] > bv || (vv[c] == bv && idx[c] < bi))) {
                bv = vv[c]; bi = idx[c];
            }
        }
    }
    for (int kbase = 512; kbase < mU; kbase += 512) {
        int idx[8]; int flc[8]; float vv[8];
#pragma unroll
        for (int c = 0; c < 8; ++c) {
            const int k = kbase + lane + (c << 6);
            idx[c] = (k < mU) ? (int)U_s[k] : 0;
        }
#pragma unroll
        for (int c = 0; c < 8; ++c) flc[c] = used_s[idx[c]];
#pragma unroll
        for (int c = 0; c < 8; ++c) vv[c] = Lr[idx[c]];
#pragma unroll
        for (int c = 0; c < 8; ++c) {
            const int k = kbase + lane + (c << 6);
            if (k < mU && flc[c] == 0 &&
                (vv[c] > bv || (vv[c] == bv && idx[c] < bi))) {
                bv = vv[c]; bi = idx[c];
            }
        }
    }
    return dpp_argmax(bv, bi);
}

// ---------------- Kernel D: sequential greedy (single wave) ----------------
// FINAL MEASURED CHAMPION (r15/r18: kD ~586us, total ~808us; reproduced
// bit-identically twice). Structure ledger:
//  - ballot fast path over kC's rank-ordered top-256 (4 resident ranks/row,
//    pipelined T loads, flag prefetch one row ahead).
//  - fallback: exact masked argmax over compact unused list; U16 register
//    cache removes idx-LDS from the chain; DPP argmax (r6) replaces the
//    bpermute reduce; flag gather stays (hides under value gather, r17).
//  - TIGHT mode: after a full-fallback group, drop ballot preamble entirely.
// Closed branches (all measured): value prefetch (r5/r7/r16), register rings
// (r11/r13), LDS-DMA ring (r12), producer waves (r9/r10), dense rows (r11),
// register used-mask (r17), deeper candidate lists (r19). The ~500cy
// scattered gather on ~1100 late-row fallbacks is the compulsory floor of
// this serial-decision chain.
__global__ __launch_bounds__(64) void kD(const float* __restrict__ L,
                                         const unsigned short* __restrict__ top,
                                         int* __restrict__ assign) {
    __shared__ int used_s[NS];
    __shared__ int assign_s[NS];
    __shared__ unsigned short U_s[NS];
    const int lane = threadIdx.x;
    for (int k = lane; k < NS; k += 64) used_s[k] = 0;
    __syncthreads();

    const uint2* __restrict__ T = (const uint2*)top;   // T[row*64 + lane]

    uint2 buf[16];           // rows g..g+15
#pragma unroll
    for (int k = 0; k < 16; ++k) buf[k] = T[k * 64 + lane];

    int f0 = 0, f1 = 0, f2 = 0, f3 = 0;   // row-0 flags: nothing used yet
    int jprev = -1;
    int mU = NS;
    int U16[16];
    bool tight = false;

    for (int g = 0; g < NS; g += 8) {
        // ---- rebuild compact unused list every 64 rows ----
        if ((g & 63) == 0) {
            int fl[24];
#pragma unroll
            for (int k = 0; k < 24; ++k) fl[k] = used_s[lane + (k << 6)];
            int cnt = 0;
#pragma unroll
            for (int k = 0; k < 24; ++k) cnt += (fl[k] == 0);
            int incl = cnt;
#pragma unroll
            for (int o = 1; o < 64; o <<= 1) {
                const int v = __shfl_up(incl, o);
                if (lane >= o) incl += v;
            }
            int pos = incl - cnt;   // exclusive prefix
#pragma unroll
            for (int k = 0; k < 24; ++k) {
                if (fl[k] == 0) { U_s[pos] = (unsigned short)(lane + (k << 6)); ++pos; }
            }
            mU = __builtin_amdgcn_readlane(incl, 63);
            // refresh U16 register cache (single wave: LDS in-order)
#pragma unroll
            for (int c = 0; c < 16; ++c) U16[c] = (int)U_s[lane + (c << 6)];
        }

        if (!tight) {
            // issue T loads for rows g+16..g+23 (consumed 2 groups from now)
            uint2 nb[8];
#pragma unroll
            for (int k = 0; k < 8; ++k) {
                int r = g + 16 + k;
                r = (r < NS) ? r : (NS - 1);
                nb[k] = T[r * 64 + lane];
            }

            int fbcnt = 0;
#pragma unroll
            for (int q = 0; q < 8; ++q) {
                const int i = g + q;

                // prefetch used-flags for row i+1 (candidates in buf[q+1])
                const uint2 pn = buf[q + 1];
                const int n0 = (int)(pn.x & 0xFFFFu), n1 = (int)(pn.x >> 16);
                const int n2 = (int)(pn.y & 0xFFFFu), n3 = (int)(pn.y >> 16);
                const int g0 = used_s[n0 < NS ? n0 : 0];
                const int g1 = used_s[n1 < NS ? n1 : 0];
                const int g2 = used_s[n2 < NS ? n2 : 0];
                const int g3 = used_s[n3 < NS ? n3 : 0];

                const uint2 pc = buf[q];
                const int c0 = (int)(pc.x & 0xFFFFu), c1 = (int)(pc.x >> 16);
                const int c2 = (int)(pc.y & 0xFFFFu), c3 = (int)(pc.y >> 16);
                const bool a0 = (c0 < NS) && (f0 == 0) && (c0 != jprev);
                const bool a1 = (c1 < NS) && (f1 == 0) && (c1 != jprev);
                const bool a2 = (c2 < NS) && (f2 == 0) && (c2 != jprev);
                const bool a3 = (c3 < NS) && (f3 == 0) && (c3 != jprev);
                const unsigned long long b0 = __ballot(a0);
                const unsigned long long b1 = __ballot(a1);
                const unsigned long long b2 = __ballot(a2);
                const unsigned long long b3 = __ballot(a3);

                int j;
                if (b0)      j = __builtin_amdgcn_readlane(c0, __ffsll(b0) - 1);
                else if (b1) j = __builtin_amdgcn_readlane(c1, __ffsll(b1) - 1);
                else if (b2) j = __builtin_amdgcn_readlane(c2, __ffsll(b2) - 1);
                else if (b3) j = __builtin_amdgcn_readlane(c3, __ffsll(b3) - 1);
                else {
                    ++fbcnt;
                    j = fb_argmax(L, i, mU, U16, used_s, U_s, lane);
                }
                if (lane == 0) { used_s[j] = 1; assign_s[i] = j; }
                jprev = j;
                f0 = g0; f1 = g1; f2 = g2; f3 = g3;
            }

            // rotate: waits only for loads issued ~8 rows ago (fully landed)
#pragma unroll
            for (int k = 0; k < 8; ++k) buf[k] = buf[k + 8];
#pragma unroll
            for (int k = 0; k < 8; ++k) buf[k + 8] = nb[k];

            tight = (fbcnt == 8);   // full-group fallback -> ballots are dead
        } else {
            // ---- TIGHT mode: fallback-only, no ballot preamble/prefetch ----
#pragma unroll 1
            for (int q = 0; q < 8; ++q) {
                const int i = g + q;
                const int j = fb_argmax(L, i, mU, U16, used_s, U_s, lane);
                if (lane == 0) { used_s[j] = 1; assign_s[i] = j; }
            }
        }
    }

    for (int k = lane; k < NS; k += 64) assign[k] = assign_s[k];
}

// ---------------- Kernel E: emit [1536][2][64] output ----------------
__global__ __launch_bounds__(128) void kE(const float* __restrict__ sat,
                                          const float* __restrict__ uav,
                                          const int* __restrict__ assign,
                                          float* __restrict__ out) {
    const int i = blockIdx.x;
    const int t = threadIdx.x;
    if (t < 64) out[(size_t)i * 128 + t] = sat[(size_t)i * DD + t];
    else        out[(size_t)i * 128 + t] = uav[(size_t)assign[i] * DD + (t - 64)];
}

extern "C" void kernel_launch(void* const* d_in, const int* in_sizes, int n_in,
                              void* d_out, int out_size, void* d_ws, size_t ws_size,
                              hipStream_t stream) {
    const float* sat = (const float*)d_in[0];
    const float* uav = (const float*)d_in[1];
    const float* W1  = (const float*)d_in[2];
    const float* b1  = (const float*)d_in[3];
    const float* W2  = (const float*)d_in[4];
    const float* b2  = (const float*)d_in[5];
    const float* W3  = (const float*)d_in[6];
    // d_in[7] = b3: sigmoid(x+b3) monotone in x — argmax unchanged.

    float* ws = (float*)d_ws;
    float* A   = ws + OFF_A;
    float* C2  = ws + OFF_C2;
    float* L   = ws + OFF_L;
    int* assign = (int*)(ws + OFF_AS);
    unsigned short* top = (unsigned short*)(ws + OFF_A);  // aliases A/C2 (dead after kB)

    hipLaunchKernelGGL(kA, dim3(NS), dim3(64), 0, stream, sat, uav, W1, b1, A, C2);
    hipLaunchKernelGGL(kB, dim3(NS / 4, NS / 256), dim3(256), 0, stream,
                       A, C2, W2, b2, W3, L);
    hipLaunchKernelGGL(kC, dim3(NS), dim3(256), 0, stream, L, top);
    hipLaunchKernelGGL(kD, dim3(1), dim3(64), 0, stream, L, top, assign);
    hipLaunchKernelGGL(kE, dim3(NS), dim3(128), 0, stream, sat, uav, assign,
                       (float*)d_out);
}